// Round 13
// baseline (253.637 us; speedup 1.0000x reference)
//
#include <hip/hip_runtime.h>
#include <math.h>

typedef __attribute__((ext_vector_type(8))) short bf16x8;
typedef __attribute__((ext_vector_type(4))) float f32x4;
typedef __attribute__((ext_vector_type(4))) unsigned int uint32x4;
typedef __attribute__((ext_vector_type(2))) unsigned int uint32x2;
typedef unsigned int uint32;
typedef unsigned short ushort;

#define N_NODES 10000
#define E_EDGES 100000
#define T_TRI   200000
#define NORB    9
#define H_DIM   128
#define C_DIM   64
#define LSTR    68   // padded f32 LDS row stride: 272B, 16B-aligned, 2-way banks
#define BSTR    72   // bf16 tile row stride in ushorts: 144B, 16B-aligned

__device__ __forceinline__ ushort f2b_rtne(float f) {
  uint32 u = __float_as_uint(f);
  u += 0x7FFFu + ((u >> 16) & 1u);
  return (ushort)(u >> 16);
}
__device__ __forceinline__ uint32 rtne2(float a, float b) {  // low=a, high=b
  uint32 ua = __float_as_uint(a), ub = __float_as_uint(b);
  ua += 0x7FFFu + ((ua >> 16) & 1u);
  ub += 0x7FFFu + ((ub >> 16) & 1u);
  return (ua >> 16) | (ub & 0xFFFF0000u);
}
__device__ __forceinline__ uint32 trunc2(float a, float b) {
  return (__float_as_uint(a) >> 16) | (__float_as_uint(b) & 0xFFFF0000u);
}
__device__ __forceinline__ float b2f(ushort u) {
  return __uint_as_float(((uint32)u) << 16);
}
__device__ __forceinline__ float blo(uint32 u) {
  return __uint_as_float(u << 16);
}
__device__ __forceinline__ float bhi(uint32 u) {
  return __uint_as_float(u & 0xFFFF0000u);
}
__device__ __forceinline__ float silu_f(float x) {
  return x * __builtin_amdgcn_rcpf(1.0f + __expf(-x));
}
__device__ __forceinline__ float sigmoid_f(float x) {
  return __builtin_amdgcn_rcpf(1.0f + __expf(-x));
}
__device__ __forceinline__ float rl(float v, int k) {
  return __uint_as_float(__builtin_amdgcn_readlane(__float_as_uint(v), k));
}
__device__ __forceinline__ f32x4 mfma16(bf16x8 a, bf16x8 b, f32x4 c) {
  return __builtin_amdgcn_mfma_f32_16x16x32_bf16(a, b, c, 0, 0, 0);
}
// packed bf16 atomic add (gfx940+): no C++ overload in ROCm 7.2, emit directly
__device__ __forceinline__ void atom_pk_bf16(ushort* addr, uint32 val) {
  asm volatile("global_atomic_pk_add_bf16 %0, %1, off"
               :: "v"(addr), "v"(val) : "memory");
}
#define LDS_FENCE() asm volatile("s_waitcnt lgkmcnt(0)" ::: "memory")

// trunc-pack 8 consecutive f32 (16B-aligned) into a bf16x8 frag
__device__ __forceinline__ bf16x8 pack8(const float* p) {
  f32x4 v0 = *(const f32x4*)p;
  f32x4 v1 = *(const f32x4*)(p + 4);
  uint32x4 u;
  u[0] = trunc2(v0[0], v0[1]);
  u[1] = trunc2(v0[2], v0[3]);
  u[2] = trunc2(v1[0], v1[1]);
  u[3] = trunc2(v1[2], v1[3]);
  return __builtin_bit_cast(bf16x8, u);
}
__device__ __forceinline__ bf16x8 pack8v(f32x4 v0, f32x4 v1) {
  uint32x4 u;
  u[0] = trunc2(v0[0], v0[1]);
  u[1] = trunc2(v0[2], v0[3]);
  u[2] = trunc2(v1[0], v1[1]);
  u[3] = trunc2(v1[2], v1[3]);
  return __builtin_bit_cast(bf16x8, u);
}
// B-frag (RTNE, done once at kernel start) for W[K][64] row-major
__device__ __forceinline__ bf16x8 bfrag_w(const float* W, int kt, int ct, int lane) {
  const float* p = W + (size_t)(kt * 32 + ((lane >> 4) * 8)) * 64 + ct * 16 + (lane & 15);
  bf16x8 r;
#pragma unroll
  for (int b = 0; b < 8; ++b) r[b] = (short)f2b_rtne(p[(size_t)b * 64]);
  return r;
}

// K1: h = x @ w_node + b_node ; x1b = bf16(h[:,:64]); sigxkb = bf16(sigmoid(h[:,64:]))
__global__ __launch_bounds__(128) void k_node_mlp(
    const float* __restrict__ x, const float* __restrict__ w_node,
    const float* __restrict__ b_node, ushort* __restrict__ x1b,
    ushort* __restrict__ sigxkb) {
  __shared__ float xs[H_DIM];
  int n = blockIdx.x;
  int c = threadIdx.x;
  xs[c] = x[(size_t)n * H_DIM + c];
  __syncthreads();
  float acc = b_node[c];
#pragma unroll 8
  for (int k = 0; k < H_DIM; ++k)
    acc = fmaf(xs[k], w_node[k * H_DIM + c], acc);
  if (c < C_DIM)
    x1b[(size_t)n * C_DIM + c] = f2b_rtne(acc);
  else
    sigxkb[(size_t)n * C_DIM + (c - C_DIM)] = f2b_rtne(sigmoid_f(acc));
}

// K2 v5: cji2 = silu(silu(cji @ w_c1) @ w_c2). R10 structure (coalesced
// loads/stores, prefetch) but layer 2 uses swapped-operand MFMA so the
// lane owns its row's channels: convert in-register, 4x ds_write_b64 into
// a bf16 tile (aliasing the dead f32 tile; DS ops are in-order per wave),
// fence, 2x ds_read_b128, identical coalesced global stores.
__global__ __launch_bounds__(256) void k_cji_mlp_mfma(
    const float* __restrict__ cji, const float* __restrict__ w_c1,
    const float* __restrict__ w_c2, ushort* __restrict__ cji2) {
  __shared__ __align__(16) float lds_all[4][16 * LSTR];
  int lane = threadIdx.x & 63;
  float* lds = lds_all[threadIdx.x >> 6];
  ushort* ldsb = (ushort*)lds;  // bf16 [16][BSTR] tile alias (2304B < 4352B)
  int wid = (blockIdx.x * 256 + (int)threadIdx.x) >> 6;
  int nw = (gridDim.x * 256) >> 6;
  bf16x8 w1f[2][4], w2f[2][4];
#pragma unroll
  for (int kt = 0; kt < 2; ++kt)
#pragma unroll
    for (int ct = 0; ct < 4; ++ct) {
      w1f[kt][ct] = bfrag_w(w_c1, kt, ct, lane);
      w2f[kt][ct] = bfrag_w(w_c2, kt, ct, lane);
    }
  const int nstrips = (E_EDGES * NORB) / 16;  // 56250
  int l15 = lane & 15, g = lane >> 4;
  int wrow = g * 4, wcol = l15;
  f32x4 z = {0.f, 0.f, 0.f, 0.f};
  int s = wid;
  f32x4 nv0, nv1, nv2, nv3;
  if (s < nstrips) {
    const float* ap = cji + (size_t)(s * 16 + l15) * 64 + g * 8;
    nv0 = *(const f32x4*)ap;
    nv1 = *(const f32x4*)(ap + 4);
    nv2 = *(const f32x4*)(ap + 32);
    nv3 = *(const f32x4*)(ap + 36);
  }
  while (s < nstrips) {
    f32x4 c0 = nv0, c1 = nv1, c2 = nv2, c3 = nv3;
    int sn = s + nw;
    if (sn < nstrips) {  // issue next-strip loads; they stay in flight
      const float* np = cji + (size_t)(sn * 16 + l15) * 64 + g * 8;
      nv0 = *(const f32x4*)np;
      nv1 = *(const f32x4*)(np + 4);
      nv2 = *(const f32x4*)(np + 32);
      nv3 = *(const f32x4*)(np + 36);
    }
    bf16x8 a0 = pack8v(c0, c1), a1 = pack8v(c2, c3);
    // layer 1 (standard): lane -> col ct*16+l15, rows wrow..+3 (f32 tile)
#pragma unroll
    for (int ct = 0; ct < 4; ++ct) {
      f32x4 acc = mfma16(a0, w1f[0][ct], z);
      acc = mfma16(a1, w1f[1][ct], acc);
#pragma unroll
      for (int r = 0; r < 4; ++r)
        lds[(wrow + r) * LSTR + ct * 16 + wcol] = silu_f(acc[r]);
    }
    LDS_FENCE();
    bf16x8 t0 = pack8(lds + l15 * LSTR + g * 8);
    bf16x8 t1 = pack8(lds + l15 * LSTR + 32 + g * 8);
    // layer 2 (swapped): lane -> row l15, channels ct*16+4g..+3; convert
    // in-register and write b64 into the bf16 tile (in-order DS => alias ok)
#pragma unroll
    for (int ct = 0; ct < 4; ++ct) {
      f32x4 acc = mfma16(w2f[0][ct], t0, z);
      acc = mfma16(w2f[1][ct], t1, acc);
      uint32x2 p;
      p[0] = rtne2(silu_f(acc[0]), silu_f(acc[1]));
      p[1] = rtne2(silu_f(acc[2]), silu_f(acc[3]));
      *(uint32x2*)(ldsb + (size_t)l15 * BSTR + ct * 16 + 4 * g) = p;
    }
    LDS_FENCE();
    const uint32x4* rp = (const uint32x4*)(ldsb + (size_t)l15 * BSTR + g * 16);
    uint32x4 q0 = rp[0], q1 = rp[1];
    uint32x4* dst = (uint32x4*)(cji2 + (size_t)(s * 16 + l15) * 64 + g * 16);
    dst[0] = q0;
    dst[1] = q1;
    s = sn;
  }
}

// K3: TWO triplets per wave; lane l owns channel pair {2l,2l+1}; one
// packed-bf16 atomic per lane (validated R10).
__global__ __launch_bounds__(256) void k_triplet_pk(
    const ushort* __restrict__ cji2, const float* __restrict__ rb,
    const float* __restrict__ cutoff_w, const float* __restrict__ shb,
    const int* __restrict__ tri_idx_k, const int* __restrict__ edge_idx_kj,
    const int* __restrict__ edge_idx_ji, const ushort* __restrict__ sigxkb,
    ushort* __restrict__ aggb) {
  int lane = threadIdx.x & 63;
  int half = lane >> 5;   // which triplet of the pair
  int l = lane & 31;      // channel-pair index
  int wid = (blockIdx.x * 256 + (int)threadIdx.x) >> 6;
  int nw = (gridDim.x * 256) >> 6;
  const uint32* c2 = (const uint32*)cji2;
  const uint32* sx = (const uint32*)sigxkb;
  for (int tb = wid; tb < T_TRI / 2; tb += nw) {
    int t = tb * 2 + half;
    int e = edge_idx_kj[t];
    float cw = cutoff_w[e];
    const uint32* crow = c2 + (size_t)e * (NORB * 32);
    float a0 = 0.f, a1 = 0.f;
#pragma unroll
    for (int d = 0; d < NORB; ++d) {
      uint32 u = crow[d * 32 + l];
      float coeff = rb[e * NORB + d] * cw * shb[t * NORB + d];
      a0 = fmaf(coeff, blo(u), a0);
      a1 = fmaf(coeff, bhi(u), a1);
    }
    float ss = a0 * a0 + a1 * a1;
#pragma unroll
    for (int m = 16; m >= 1; m >>= 1) ss += __shfl_xor(ss, m, 64);  // within half
    float scale = __builtin_amdgcn_rsqf(fmaxf(ss, 1e-30f));
    int kn = tri_idx_k[t];
    uint32 gx = sx[(size_t)kn * 32 + l];
    float v0 = a0 * scale * blo(gx);
    float v1 = a1 * scale * bhi(gx);
    int ej = edge_idx_ji[t];
    atom_pk_bf16(aggb + (size_t)ej * C_DIM + 2 * l, rtne2(v0, v1));
  }
}

// K4+K5 fused: tbw = MLP(agg) (kept in LDS); lcao = normalize((1+tbw)*sum_d rb_w*cji2) @ w_basis
__global__ __launch_bounds__(256) void k_tbw_lcao(
    const ushort* __restrict__ aggb, const float* __restrict__ w_t1,
    const float* __restrict__ b_t1, const float* __restrict__ w_t2,
    const float* __restrict__ b_t2, const ushort* __restrict__ cji2,
    const float* __restrict__ rb, const float* __restrict__ cutoff_w,
    const float* __restrict__ w_basis, float* __restrict__ lcao) {
  __shared__ __align__(16) float lds_all[4][16 * LSTR];
  int lane = threadIdx.x & 63;
  float* lds = lds_all[threadIdx.x >> 6];
  int wid = (blockIdx.x * 256 + (int)threadIdx.x) >> 6;
  int nw = (gridDim.x * 256) >> 6;
  bf16x8 wt1[2][4], wt2[2][4], wb[2][4];
  float bt1[4], bt2[4];
  int l15 = lane & 15, g = lane >> 4;
#pragma unroll
  for (int ct = 0; ct < 4; ++ct) {
    bt1[ct] = b_t1[ct * 16 + l15];
    bt2[ct] = b_t2[ct * 16 + l15];
#pragma unroll
    for (int kt = 0; kt < 2; ++kt) {
      wt1[kt][ct] = bfrag_w(w_t1, kt, ct, lane);
      wt2[kt][ct] = bfrag_w(w_t2, kt, ct, lane);
      wb[kt][ct] = bfrag_w(w_basis, kt, ct, lane);
    }
  }
  const int nstrips = E_EDGES / 16;  // 6250
  int wrow = g * 4, wcol = l15;
  f32x4 z = {0.f, 0.f, 0.f, 0.f};
  for (int s = wid; s < nstrips; s += nw) {
    const uint32x4* ap = (const uint32x4*)(aggb + (size_t)(s * 16 + l15) * 64 + g * 8);
    bf16x8 a0 = __builtin_bit_cast(bf16x8, ap[0]);
    bf16x8 a1 = __builtin_bit_cast(bf16x8, ap[2]);  // +32 elems
#pragma unroll
    for (int ct = 0; ct < 4; ++ct) {
      f32x4 acc = mfma16(a0, wt1[0][ct], z);
      acc = mfma16(a1, wt1[1][ct], acc);
#pragma unroll
      for (int r = 0; r < 4; ++r)
        lds[(wrow + r) * LSTR + ct * 16 + wcol] = silu_f(acc[r] + bt1[ct]);
    }
    LDS_FENCE();
    bf16x8 t0 = pack8(lds + l15 * LSTR + g * 8);
    bf16x8 t1 = pack8(lds + l15 * LSTR + 32 + g * 8);
    LDS_FENCE();
#pragma unroll
    for (int ct = 0; ct < 4; ++ct) {
      f32x4 acc = mfma16(t0, wt2[0][ct], z);
      acc = mfma16(t1, wt2[1][ct], acc);
#pragma unroll
      for (int r = 0; r < 4; ++r)
        lds[(wrow + r) * LSTR + ct * 16 + wcol] = silu_f(acc[r] + bt2[ct]);  // tbw tile
    }
    LDS_FENCE();
    // per-edge orbital contraction, gate by (1+tbw), normalize -> overwrite tile rows
    for (int ee = 0; ee < 16; ++ee) {
      int e = s * 16 + ee;
      float cw = cutoff_w[e];
      const ushort* crow = cji2 + (size_t)e * (NORB * C_DIM);
      float acc = 0.f;
#pragma unroll
      for (int d = 0; d < NORB; ++d)
        acc = fmaf(rb[e * NORB + d] * cw, b2f(crow[d * C_DIM + lane]), acc);
      acc *= (1.0f + lds[ee * LSTR + lane]);
      float ss = acc * acc;
#pragma unroll
      for (int m = 32; m >= 1; m >>= 1) ss += __shfl_xor(ss, m, 64);
      float scale = __builtin_amdgcn_rsqf(fmaxf(ss, 1e-30f));
      lds[ee * LSTR + lane] = acc * scale;
    }
    LDS_FENCE();
    bf16x8 n0 = pack8(lds + l15 * LSTR + g * 8);
    bf16x8 n1 = pack8(lds + l15 * LSTR + 32 + g * 8);
    LDS_FENCE();
    f32x4 o[4];
#pragma unroll
    for (int ct = 0; ct < 4; ++ct) {
      o[ct] = mfma16(n0, wb[0][ct], z);
      o[ct] = mfma16(n1, wb[1][ct], o[ct]);
#pragma unroll
      for (int r = 0; r < 4; ++r)
        lds[(wrow + r) * LSTR + ct * 16 + wcol] = o[ct][r];
    }
    LDS_FENCE();
    const float* lp = lds + l15 * LSTR + g * 16;
    f32x4* dst = (f32x4*)(lcao + (size_t)(s * 16 + l15) * 64 + g * 16);
    dst[0] = *(const f32x4*)lp;
    dst[1] = *(const f32x4*)(lp + 4);
    dst[2] = *(const f32x4*)(lp + 8);
    dst[3] = *(const f32x4*)(lp + 12);
  }
}

// K6: fnode MLP + msg + scatter. pk-bf16 atomics via adjacent-lane pairing.
__global__ __launch_bounds__(256) void k_msg_mfma(
    const ushort* __restrict__ x1b, const int* __restrict__ idx_i,
    const int* __restrict__ idx_j, const float* __restrict__ w_n1,
    const float* __restrict__ b_n1, const float* __restrict__ w_n2,
    const float* __restrict__ b_n2, const float* __restrict__ lcao,
    ushort* __restrict__ nodeaggb) {
  __shared__ __align__(16) float lds_all[4][16 * LSTR];
  int lane = threadIdx.x & 63;
  float* lds = lds_all[threadIdx.x >> 6];
  int wid = (blockIdx.x * 256 + (int)threadIdx.x) >> 6;
  int nw = (gridDim.x * 256) >> 6;
  bf16x8 wn1f[4][4], wn2f[2][4];
  float bn1[4], bn2[4];
  int l15 = lane & 15, g = lane >> 4;
#pragma unroll
  for (int ct = 0; ct < 4; ++ct) {
    bn1[ct] = b_n1[ct * 16 + l15];
    bn2[ct] = b_n2[ct * 16 + l15];
#pragma unroll
    for (int kt = 0; kt < 4; ++kt) wn1f[kt][ct] = bfrag_w(w_n1, kt, ct, lane);
#pragma unroll
    for (int kt = 0; kt < 2; ++kt) wn2f[kt][ct] = bfrag_w(w_n2, kt, ct, lane);
  }
  const int nstrips = E_EDGES / 16;
  int wrow = g * 4, wcol = l15;
  f32x4 z = {0.f, 0.f, 0.f, 0.f};
  for (int s = wid; s < nstrips; s += nw) {
    int er = s * 16 + l15;
    int ii = idx_i[er], jj = idx_j[er];
    const uint32x4* pi = (const uint32x4*)(x1b + (size_t)ii * 64 + g * 8);
    const uint32x4* pj = (const uint32x4*)(x1b + (size_t)jj * 64 + g * 8);
    bf16x8 a0 = __builtin_bit_cast(bf16x8, pi[0]);
    bf16x8 a1 = __builtin_bit_cast(bf16x8, pi[2]);  // +32 elems = +2 uint32x4
    bf16x8 a2 = __builtin_bit_cast(bf16x8, pj[0]);
    bf16x8 a3 = __builtin_bit_cast(bf16x8, pj[2]);
#pragma unroll
    for (int ct = 0; ct < 4; ++ct) {
      f32x4 acc = mfma16(a0, wn1f[0][ct], z);
      acc = mfma16(a1, wn1f[1][ct], acc);
      acc = mfma16(a2, wn1f[2][ct], acc);
      acc = mfma16(a3, wn1f[3][ct], acc);
#pragma unroll
      for (int r = 0; r < 4; ++r)
        lds[(wrow + r) * LSTR + ct * 16 + wcol] = silu_f(acc[r] + bn1[ct]);
    }
    LDS_FENCE();
    bf16x8 t0 = pack8(lds + l15 * LSTR + g * 8);
    bf16x8 t1 = pack8(lds + l15 * LSTR + 32 + g * 8);
    f32x4 acc2[4];
#pragma unroll
    for (int ct = 0; ct < 4; ++ct) {
      acc2[ct] = mfma16(t0, wn2f[0][ct], z);
      acc2[ct] = mfma16(t1, wn2f[1][ct], acc2[ct]);
    }
#pragma unroll
    for (int r = 0; r < 4; ++r) {
      int ge = s * 16 + wrow + r;
      int ni = idx_i[ge];
#pragma unroll
      for (int ct = 0; ct < 4; ++ct) {
        float f = silu_f(acc2[ct][r] + bn2[ct]);
        float m = lcao[(size_t)ge * 64 + ct * 16 + l15] * f;
        float mn = __shfl_xor(m, 1, 64);  // adjacent channel's value
        if (!(l15 & 1))
          atom_pk_bf16(nodeaggb + (size_t)ni * 64 + ct * 16 + l15, rtne2(m, mn));
      }
    }
  }
}

// K7: out = x + nodeagg @ w_out (nodeagg bf16)
__global__ __launch_bounds__(256) void k_out(
    const float* __restrict__ x, const ushort* __restrict__ nodeaggb,
    const float* __restrict__ w_out, float* __restrict__ out) {
  int lane = threadIdx.x & 63;
  int wid = (blockIdx.x * 256 + (int)threadIdx.x) >> 6;
  int nw = (gridDim.x * 256) >> 6;
  float wo0[64], wo1[64];
#pragma unroll
  for (int k = 0; k < 64; ++k) wo0[k] = w_out[k * H_DIM + lane];
#pragma unroll
  for (int k = 0; k < 64; ++k) wo1[k] = w_out[k * H_DIM + 64 + lane];
  for (int n = wid; n < N_NODES; n += nw) {
    float v = b2f(nodeaggb[(size_t)n * 64 + lane]);
    float a0 = 0.f, a1 = 0.f;
#pragma unroll
    for (int k = 0; k < 64; ++k) {
      float a = rl(v, k);
      a0 = fmaf(a, wo0[k], a0);
      a1 = fmaf(a, wo1[k], a1);
    }
    out[(size_t)n * H_DIM + lane] = x[(size_t)n * H_DIM + lane] + a0;
    out[(size_t)n * H_DIM + 64 + lane] = x[(size_t)n * H_DIM + 64 + lane] + a1;
  }
}

extern "C" void kernel_launch(void* const* d_in, const int* in_sizes, int n_in,
                              void* d_out, int out_size, void* d_ws, size_t ws_size,
                              hipStream_t stream) {
  const float* x         = (const float*)d_in[0];
  const float* cji       = (const float*)d_in[1];
  const float* cutoff_w  = (const float*)d_in[2];
  const float* rb        = (const float*)d_in[3];
  const float* shb       = (const float*)d_in[4];
  const int*   idx_i     = (const int*)d_in[5];
  const int*   idx_j     = (const int*)d_in[6];
  const int*   tri_idx_k = (const int*)d_in[7];
  const int*   e_kj      = (const int*)d_in[8];
  const int*   e_ji      = (const int*)d_in[9];
  const float* w_node    = (const float*)d_in[10];
  const float* b_node    = (const float*)d_in[11];
  const float* w_c1      = (const float*)d_in[12];
  const float* w_c2      = (const float*)d_in[13];
  const float* w_t1      = (const float*)d_in[14];
  const float* b_t1      = (const float*)d_in[15];
  const float* w_t2      = (const float*)d_in[16];
  const float* b_t2      = (const float*)d_in[17];
  const float* w_basis   = (const float*)d_in[18];
  const float* w_n1      = (const float*)d_in[19];
  const float* b_n1      = (const float*)d_in[20];
  const float* w_n2      = (const float*)d_in[21];
  const float* b_n2      = (const float*)d_in[22];
  const float* w_out     = (const float*)d_in[23];
  float* out = (float*)d_out;

  char* ws = (char*)d_ws;
  ushort* x1b     = (ushort*)(ws + 0);            //   1,280,000 B
  ushort* sigxkb  = (ushort*)(ws + 1280000);      //   1,280,000 B
  ushort* cji2    = (ushort*)(ws + 2560000);      // 115,200,000 B
  ushort* aggb    = (ushort*)(ws + 117760000);    //  12,800,000 B (bf16 agg)
  float*  lcao    = (float*)(ws + 143360000);     //  25,600,000 B
  ushort* nodeaggb= (ushort*)(ws + 168960000);    //   1,280,000 B (bf16)

  (void)hipMemsetAsync(aggb, 0, (size_t)6400000 * sizeof(ushort), stream);
  (void)hipMemsetAsync(nodeaggb, 0, (size_t)640000 * sizeof(ushort), stream);

  k_node_mlp<<<N_NODES, 128, 0, stream>>>(x, w_node, b_node, x1b, sigxkb);
  k_cji_mlp_mfma<<<2048, 256, 0, stream>>>(cji, w_c1, w_c2, cji2);
  k_triplet_pk<<<2048, 256, 0, stream>>>(cji2, rb, cutoff_w, shb, tri_idx_k,
                                         e_kj, e_ji, sigxkb, aggb);
  k_tbw_lcao<<<1024, 256, 0, stream>>>(aggb, w_t1, b_t1, w_t2, b_t2, cji2,
                                       rb, cutoff_w, w_basis, lcao);
  k_msg_mfma<<<1024, 256, 0, stream>>>(x1b, idx_i, idx_j, w_n1, b_n1, w_n2,
                                       b_n2, lcao, nodeaggb);
  k_out<<<256, 256, 0, stream>>>(x, nodeaggb, w_out, out);
}

// Round 14
// 252.295 us; speedup vs baseline: 1.0053x; 1.0053x over previous
//
#include <hip/hip_runtime.h>
#include <math.h>

typedef __attribute__((ext_vector_type(8))) short bf16x8;
typedef __attribute__((ext_vector_type(4))) float f32x4;
typedef __attribute__((ext_vector_type(4))) unsigned int uint32x4;
typedef unsigned int uint32;
typedef unsigned short ushort;

#define N_NODES 10000
#define E_EDGES 100000
#define T_TRI   200000
#define NORB    9
#define H_DIM   128
#define C_DIM   64
#define LSTR    68   // padded LDS row stride (floats): 272B, 16B-aligned, 2-way banks

__device__ __forceinline__ ushort f2b_rtne(float f) {
  uint32 u = __float_as_uint(f);
  u += 0x7FFFu + ((u >> 16) & 1u);
  return (ushort)(u >> 16);
}
__device__ __forceinline__ uint32 rtne2(float a, float b) {  // low=a, high=b
  uint32 ua = __float_as_uint(a), ub = __float_as_uint(b);
  ua += 0x7FFFu + ((ua >> 16) & 1u);
  ub += 0x7FFFu + ((ub >> 16) & 1u);
  return (ua >> 16) | (ub & 0xFFFF0000u);
}
__device__ __forceinline__ uint32 trunc2(float a, float b) {
  return (__float_as_uint(a) >> 16) | (__float_as_uint(b) & 0xFFFF0000u);
}
__device__ __forceinline__ float b2f(ushort u) {
  return __uint_as_float(((uint32)u) << 16);
}
__device__ __forceinline__ float blo(uint32 u) {
  return __uint_as_float(u << 16);
}
__device__ __forceinline__ float bhi(uint32 u) {
  return __uint_as_float(u & 0xFFFF0000u);
}
__device__ __forceinline__ float silu_f(float x) {
  return x * __builtin_amdgcn_rcpf(1.0f + __expf(-x));
}
__device__ __forceinline__ float sigmoid_f(float x) {
  return __builtin_amdgcn_rcpf(1.0f + __expf(-x));
}
__device__ __forceinline__ float rl(float v, int k) {
  return __uint_as_float(__builtin_amdgcn_readlane(__float_as_uint(v), k));
}
__device__ __forceinline__ f32x4 mfma16(bf16x8 a, bf16x8 b, f32x4 c) {
  return __builtin_amdgcn_mfma_f32_16x16x32_bf16(a, b, c, 0, 0, 0);
}
// packed bf16 atomic add (gfx940+): no C++ overload in ROCm 7.2, emit directly
__device__ __forceinline__ void atom_pk_bf16(ushort* addr, uint32 val) {
  asm volatile("global_atomic_pk_add_bf16 %0, %1, off"
               :: "v"(addr), "v"(val) : "memory");
}
#define LDS_FENCE() asm volatile("s_waitcnt lgkmcnt(0)" ::: "memory")

// trunc-pack 8 consecutive f32 (16B-aligned) into a bf16x8 frag
__device__ __forceinline__ bf16x8 pack8(const float* p) {
  f32x4 v0 = *(const f32x4*)p;
  f32x4 v1 = *(const f32x4*)(p + 4);
  uint32x4 u;
  u[0] = trunc2(v0[0], v0[1]);
  u[1] = trunc2(v0[2], v0[3]);
  u[2] = trunc2(v1[0], v1[1]);
  u[3] = trunc2(v1[2], v1[3]);
  return __builtin_bit_cast(bf16x8, u);
}
__device__ __forceinline__ bf16x8 pack8v(f32x4 v0, f32x4 v1) {
  uint32x4 u;
  u[0] = trunc2(v0[0], v0[1]);
  u[1] = trunc2(v0[2], v0[3]);
  u[2] = trunc2(v1[0], v1[1]);
  u[3] = trunc2(v1[2], v1[3]);
  return __builtin_bit_cast(bf16x8, u);
}
// B-frag (RTNE, done once at kernel start) for W[K][64] row-major
__device__ __forceinline__ bf16x8 bfrag_w(const float* W, int kt, int ct, int lane) {
  const float* p = W + (size_t)(kt * 32 + ((lane >> 4) * 8)) * 64 + ct * 16 + (lane & 15);
  bf16x8 r;
#pragma unroll
  for (int b = 0; b < 8; ++b) r[b] = (short)f2b_rtne(p[(size_t)b * 64]);
  return r;
}

// K1: h = x @ w_node + b_node ; x1b = bf16(h[:,:64]); sigxkb = bf16(sigmoid(h[:,64:]))
__global__ __launch_bounds__(128) void k_node_mlp(
    const float* __restrict__ x, const float* __restrict__ w_node,
    const float* __restrict__ b_node, ushort* __restrict__ x1b,
    ushort* __restrict__ sigxkb) {
  __shared__ float xs[H_DIM];
  int n = blockIdx.x;
  int c = threadIdx.x;
  xs[c] = x[(size_t)n * H_DIM + c];
  __syncthreads();
  float acc = b_node[c];
#pragma unroll 8
  for (int k = 0; k < H_DIM; ++k)
    acc = fmaf(xs[k], w_node[k * H_DIM + c], acc);
  if (c < C_DIM)
    x1b[(size_t)n * C_DIM + c] = f2b_rtne(acc);
  else
    sigxkb[(size_t)n * C_DIM + (c - C_DIM)] = f2b_rtne(sigmoid_f(acc));
}

// K2 (R10/R12 version): cji2 = silu(silu(cji @ w_c1) @ w_c2). Coalesced
// structure + software-pipelined global prefetch of the next strip.
__global__ __launch_bounds__(256) void k_cji_mlp_mfma(
    const float* __restrict__ cji, const float* __restrict__ w_c1,
    const float* __restrict__ w_c2, ushort* __restrict__ cji2) {
  __shared__ __align__(16) float lds_all[4][16 * LSTR];
  int lane = threadIdx.x & 63;
  float* lds = lds_all[threadIdx.x >> 6];
  int wid = (blockIdx.x * 256 + (int)threadIdx.x) >> 6;
  int nw = (gridDim.x * 256) >> 6;
  bf16x8 w1f[2][4], w2f[2][4];
#pragma unroll
  for (int kt = 0; kt < 2; ++kt)
#pragma unroll
    for (int ct = 0; ct < 4; ++ct) {
      w1f[kt][ct] = bfrag_w(w_c1, kt, ct, lane);
      w2f[kt][ct] = bfrag_w(w_c2, kt, ct, lane);
    }
  const int nstrips = (E_EDGES * NORB) / 16;  // 56250
  int l15 = lane & 15, g = lane >> 4;
  int wrow = g * 4, wcol = l15;
  f32x4 z = {0.f, 0.f, 0.f, 0.f};
  int s = wid;
  f32x4 nv0, nv1, nv2, nv3;
  if (s < nstrips) {
    const float* ap = cji + (size_t)(s * 16 + l15) * 64 + g * 8;
    nv0 = *(const f32x4*)ap;
    nv1 = *(const f32x4*)(ap + 4);
    nv2 = *(const f32x4*)(ap + 32);
    nv3 = *(const f32x4*)(ap + 36);
  }
  while (s < nstrips) {
    f32x4 c0 = nv0, c1 = nv1, c2 = nv2, c3 = nv3;
    int sn = s + nw;
    if (sn < nstrips) {  // issue next-strip loads; they stay in flight
      const float* np = cji + (size_t)(sn * 16 + l15) * 64 + g * 8;
      nv0 = *(const f32x4*)np;
      nv1 = *(const f32x4*)(np + 4);
      nv2 = *(const f32x4*)(np + 32);
      nv3 = *(const f32x4*)(np + 36);
    }
    bf16x8 a0 = pack8v(c0, c1), a1 = pack8v(c2, c3);
#pragma unroll
    for (int ct = 0; ct < 4; ++ct) {
      f32x4 acc = mfma16(a0, w1f[0][ct], z);
      acc = mfma16(a1, w1f[1][ct], acc);
#pragma unroll
      for (int r = 0; r < 4; ++r)
        lds[(wrow + r) * LSTR + ct * 16 + wcol] = silu_f(acc[r]);
    }
    LDS_FENCE();
    bf16x8 t0 = pack8(lds + l15 * LSTR + g * 8);
    bf16x8 t1 = pack8(lds + l15 * LSTR + 32 + g * 8);
#pragma unroll
    for (int ct = 0; ct < 4; ++ct) {
      f32x4 acc = mfma16(t0, w2f[0][ct], z);
      acc = mfma16(t1, w2f[1][ct], acc);
#pragma unroll
      for (int r = 0; r < 4; ++r)
        lds[(wrow + r) * LSTR + ct * 16 + wcol] = silu_f(acc[r]);
    }
    LDS_FENCE();
    const float* lp = lds + l15 * LSTR + g * 16;
    f32x4 v0 = *(const f32x4*)lp;
    f32x4 v1 = *(const f32x4*)(lp + 4);
    f32x4 v2 = *(const f32x4*)(lp + 8);
    f32x4 v3 = *(const f32x4*)(lp + 12);
    uint32x4 o0, o1;
    o0[0] = rtne2(v0[0], v0[1]); o0[1] = rtne2(v0[2], v0[3]);
    o0[2] = rtne2(v1[0], v1[1]); o0[3] = rtne2(v1[2], v1[3]);
    o1[0] = rtne2(v2[0], v2[1]); o1[1] = rtne2(v2[2], v2[3]);
    o1[2] = rtne2(v3[0], v3[1]); o1[3] = rtne2(v3[2], v3[3]);
    uint32x4* dst = (uint32x4*)(cji2 + (size_t)(s * 16 + l15) * 64 + g * 16);
    dst[0] = o0;
    dst[1] = o1;
    s = sn;
  }
}

// K3: TWO triplets per wave; lane l owns channel pair {2l,2l+1}; one
// packed-bf16 atomic per lane (validated R10).
__global__ __launch_bounds__(256) void k_triplet_pk(
    const ushort* __restrict__ cji2, const float* __restrict__ rb,
    const float* __restrict__ cutoff_w, const float* __restrict__ shb,
    const int* __restrict__ tri_idx_k, const int* __restrict__ edge_idx_kj,
    const int* __restrict__ edge_idx_ji, const ushort* __restrict__ sigxkb,
    ushort* __restrict__ aggb) {
  int lane = threadIdx.x & 63;
  int half = lane >> 5;   // which triplet of the pair
  int l = lane & 31;      // channel-pair index
  int wid = (blockIdx.x * 256 + (int)threadIdx.x) >> 6;
  int nw = (gridDim.x * 256) >> 6;
  const uint32* c2 = (const uint32*)cji2;
  const uint32* sx = (const uint32*)sigxkb;
  for (int tb = wid; tb < T_TRI / 2; tb += nw) {
    int t = tb * 2 + half;
    int e = edge_idx_kj[t];
    float cw = cutoff_w[e];
    const uint32* crow = c2 + (size_t)e * (NORB * 32);
    float a0 = 0.f, a1 = 0.f;
#pragma unroll
    for (int d = 0; d < NORB; ++d) {
      uint32 u = crow[d * 32 + l];
      float coeff = rb[e * NORB + d] * cw * shb[t * NORB + d];
      a0 = fmaf(coeff, blo(u), a0);
      a1 = fmaf(coeff, bhi(u), a1);
    }
    float ss = a0 * a0 + a1 * a1;
#pragma unroll
    for (int m = 16; m >= 1; m >>= 1) ss += __shfl_xor(ss, m, 64);  // within half
    float scale = __builtin_amdgcn_rsqf(fmaxf(ss, 1e-30f));
    int kn = tri_idx_k[t];
    uint32 gx = sx[(size_t)kn * 32 + l];
    float v0 = a0 * scale * blo(gx);
    float v1 = a1 * scale * bhi(gx);
    int ej = edge_idx_ji[t];
    atom_pk_bf16(aggb + (size_t)ej * C_DIM + 2 * l, rtne2(v0, v1));
  }
}

// K4+K5 fused: tbw = MLP(agg) (kept in LDS);
// lcao = bf16( normalize((1+tbw)*sum_d rb_w*cji2) @ w_basis ).
// FIX: kt=1 A-frag of aggb is ap[4] (+32 bf16 elems), not ap[2] (+16).
__global__ __launch_bounds__(256) void k_tbw_lcao(
    const ushort* __restrict__ aggb, const float* __restrict__ w_t1,
    const float* __restrict__ b_t1, const float* __restrict__ w_t2,
    const float* __restrict__ b_t2, const ushort* __restrict__ cji2,
    const float* __restrict__ rb, const float* __restrict__ cutoff_w,
    const float* __restrict__ w_basis, ushort* __restrict__ lcaob) {
  __shared__ __align__(16) float lds_all[4][16 * LSTR];
  int lane = threadIdx.x & 63;
  float* lds = lds_all[threadIdx.x >> 6];
  int wid = (blockIdx.x * 256 + (int)threadIdx.x) >> 6;
  int nw = (gridDim.x * 256) >> 6;
  bf16x8 wt1[2][4], wt2[2][4], wb[2][4];
  float bt1[4], bt2[4];
  int l15 = lane & 15, g = lane >> 4;
#pragma unroll
  for (int ct = 0; ct < 4; ++ct) {
    bt1[ct] = b_t1[ct * 16 + l15];
    bt2[ct] = b_t2[ct * 16 + l15];
#pragma unroll
    for (int kt = 0; kt < 2; ++kt) {
      wt1[kt][ct] = bfrag_w(w_t1, kt, ct, lane);
      wt2[kt][ct] = bfrag_w(w_t2, kt, ct, lane);
      wb[kt][ct] = bfrag_w(w_basis, kt, ct, lane);
    }
  }
  const int nstrips = E_EDGES / 16;  // 6250
  int wrow = g * 4, wcol = l15;
  f32x4 z = {0.f, 0.f, 0.f, 0.f};
  for (int s = wid; s < nstrips; s += nw) {
    const uint32x4* ap = (const uint32x4*)(aggb + (size_t)(s * 16 + l15) * 64 + g * 8);
    bf16x8 a0 = __builtin_bit_cast(bf16x8, ap[0]);
    bf16x8 a1 = __builtin_bit_cast(bf16x8, ap[4]);  // +32 bf16 elems (FIXED)
#pragma unroll
    for (int ct = 0; ct < 4; ++ct) {
      f32x4 acc = mfma16(a0, wt1[0][ct], z);
      acc = mfma16(a1, wt1[1][ct], acc);
#pragma unroll
      for (int r = 0; r < 4; ++r)
        lds[(wrow + r) * LSTR + ct * 16 + wcol] = silu_f(acc[r] + bt1[ct]);
    }
    LDS_FENCE();
    bf16x8 t0 = pack8(lds + l15 * LSTR + g * 8);
    bf16x8 t1 = pack8(lds + l15 * LSTR + 32 + g * 8);
    LDS_FENCE();
#pragma unroll
    for (int ct = 0; ct < 4; ++ct) {
      f32x4 acc = mfma16(t0, wt2[0][ct], z);
      acc = mfma16(t1, wt2[1][ct], acc);
#pragma unroll
      for (int r = 0; r < 4; ++r)
        lds[(wrow + r) * LSTR + ct * 16 + wcol] = silu_f(acc[r] + bt2[ct]);  // tbw tile
    }
    LDS_FENCE();
    // per-edge orbital contraction, gate by (1+tbw), normalize -> overwrite tile rows
    for (int ee = 0; ee < 16; ++ee) {
      int e = s * 16 + ee;
      float cw = cutoff_w[e];
      const ushort* crow = cji2 + (size_t)e * (NORB * C_DIM);
      float acc = 0.f;
#pragma unroll
      for (int d = 0; d < NORB; ++d)
        acc = fmaf(rb[e * NORB + d] * cw, b2f(crow[d * C_DIM + lane]), acc);
      acc *= (1.0f + lds[ee * LSTR + lane]);
      float ss = acc * acc;
#pragma unroll
      for (int m = 32; m >= 1; m >>= 1) ss += __shfl_xor(ss, m, 64);
      float scale = __builtin_amdgcn_rsqf(fmaxf(ss, 1e-30f));
      lds[ee * LSTR + lane] = acc * scale;
    }
    LDS_FENCE();
    bf16x8 n0 = pack8(lds + l15 * LSTR + g * 8);
    bf16x8 n1 = pack8(lds + l15 * LSTR + 32 + g * 8);
    LDS_FENCE();
    f32x4 o[4];
#pragma unroll
    for (int ct = 0; ct < 4; ++ct) {
      o[ct] = mfma16(n0, wb[0][ct], z);
      o[ct] = mfma16(n1, wb[1][ct], o[ct]);
#pragma unroll
      for (int r = 0; r < 4; ++r)
        lds[(wrow + r) * LSTR + ct * 16 + wcol] = o[ct][r];
    }
    LDS_FENCE();
    const float* lp = lds + l15 * LSTR + g * 16;
    f32x4 v0 = *(const f32x4*)lp;
    f32x4 v1 = *(const f32x4*)(lp + 4);
    f32x4 v2 = *(const f32x4*)(lp + 8);
    f32x4 v3 = *(const f32x4*)(lp + 12);
    uint32x4 o0, o1;
    o0[0] = rtne2(v0[0], v0[1]); o0[1] = rtne2(v0[2], v0[3]);
    o0[2] = rtne2(v1[0], v1[1]); o0[3] = rtne2(v1[2], v1[3]);
    o1[0] = rtne2(v2[0], v2[1]); o1[1] = rtne2(v2[2], v2[3]);
    o1[2] = rtne2(v3[0], v3[1]); o1[3] = rtne2(v3[2], v3[3]);
    uint32x4* dst = (uint32x4*)(lcaob + (size_t)(s * 16 + l15) * 64 + g * 16);
    dst[0] = o0;
    dst[1] = o1;
  }
}

// K6: fnode MLP + msg + scatter. pk-bf16 atomics via adjacent-lane pairing.
// FIX: kt=1 frags of x1 are pi[4]/pj[4] (+32 bf16 elems), not pi[2]/pj[2].
__global__ __launch_bounds__(256) void k_msg_mfma(
    const ushort* __restrict__ x1b, const int* __restrict__ idx_i,
    const int* __restrict__ idx_j, const float* __restrict__ w_n1,
    const float* __restrict__ b_n1, const float* __restrict__ w_n2,
    const float* __restrict__ b_n2, const ushort* __restrict__ lcaob,
    ushort* __restrict__ nodeaggb) {
  __shared__ __align__(16) float lds_all[4][16 * LSTR];
  int lane = threadIdx.x & 63;
  float* lds = lds_all[threadIdx.x >> 6];
  int wid = (blockIdx.x * 256 + (int)threadIdx.x) >> 6;
  int nw = (gridDim.x * 256) >> 6;
  bf16x8 wn1f[4][4], wn2f[2][4];
  float bn1[4], bn2[4];
  int l15 = lane & 15, g = lane >> 4;
#pragma unroll
  for (int ct = 0; ct < 4; ++ct) {
    bn1[ct] = b_n1[ct * 16 + l15];
    bn2[ct] = b_n2[ct * 16 + l15];
#pragma unroll
    for (int kt = 0; kt < 4; ++kt) wn1f[kt][ct] = bfrag_w(w_n1, kt, ct, lane);
#pragma unroll
    for (int kt = 0; kt < 2; ++kt) wn2f[kt][ct] = bfrag_w(w_n2, kt, ct, lane);
  }
  const int nstrips = E_EDGES / 16;
  int wrow = g * 4, wcol = l15;
  f32x4 z = {0.f, 0.f, 0.f, 0.f};
  for (int s = wid; s < nstrips; s += nw) {
    int er = s * 16 + l15;
    int ii = idx_i[er], jj = idx_j[er];
    const uint32x4* pi = (const uint32x4*)(x1b + (size_t)ii * 64 + g * 8);
    const uint32x4* pj = (const uint32x4*)(x1b + (size_t)jj * 64 + g * 8);
    bf16x8 a0 = __builtin_bit_cast(bf16x8, pi[0]);
    bf16x8 a1 = __builtin_bit_cast(bf16x8, pi[4]);  // +32 bf16 elems (FIXED)
    bf16x8 a2 = __builtin_bit_cast(bf16x8, pj[0]);
    bf16x8 a3 = __builtin_bit_cast(bf16x8, pj[4]);  // +32 bf16 elems (FIXED)
#pragma unroll
    for (int ct = 0; ct < 4; ++ct) {
      f32x4 acc = mfma16(a0, wn1f[0][ct], z);
      acc = mfma16(a1, wn1f[1][ct], acc);
      acc = mfma16(a2, wn1f[2][ct], acc);
      acc = mfma16(a3, wn1f[3][ct], acc);
#pragma unroll
      for (int r = 0; r < 4; ++r)
        lds[(wrow + r) * LSTR + ct * 16 + wcol] = silu_f(acc[r] + bn1[ct]);
    }
    LDS_FENCE();
    bf16x8 t0 = pack8(lds + l15 * LSTR + g * 8);
    bf16x8 t1 = pack8(lds + l15 * LSTR + 32 + g * 8);
    f32x4 acc2[4];
#pragma unroll
    for (int ct = 0; ct < 4; ++ct) {
      acc2[ct] = mfma16(t0, wn2f[0][ct], z);
      acc2[ct] = mfma16(t1, wn2f[1][ct], acc2[ct]);
    }
#pragma unroll
    for (int r = 0; r < 4; ++r) {
      int ge = s * 16 + wrow + r;
      int ni = idx_i[ge];
#pragma unroll
      for (int ct = 0; ct < 4; ++ct) {
        float f = silu_f(acc2[ct][r] + bn2[ct]);
        float m = b2f(lcaob[(size_t)ge * 64 + ct * 16 + l15]) * f;
        float mn = __shfl_xor(m, 1, 64);  // adjacent channel's value
        if (!(l15 & 1))
          atom_pk_bf16(nodeaggb + (size_t)ni * 64 + ct * 16 + l15, rtne2(m, mn));
      }
    }
  }
}

// K7: out = x + nodeagg @ w_out (nodeagg bf16)
__global__ __launch_bounds__(256) void k_out(
    const float* __restrict__ x, const ushort* __restrict__ nodeaggb,
    const float* __restrict__ w_out, float* __restrict__ out) {
  int lane = threadIdx.x & 63;
  int wid = (blockIdx.x * 256 + (int)threadIdx.x) >> 6;
  int nw = (gridDim.x * 256) >> 6;
  float wo0[64], wo1[64];
#pragma unroll
  for (int k = 0; k < 64; ++k) wo0[k] = w_out[k * H_DIM + lane];
#pragma unroll
  for (int k = 0; k < 64; ++k) wo1[k] = w_out[k * H_DIM + 64 + lane];
  for (int n = wid; n < N_NODES; n += nw) {
    float v = b2f(nodeaggb[(size_t)n * 64 + lane]);
    float a0 = 0.f, a1 = 0.f;
#pragma unroll
    for (int k = 0; k < 64; ++k) {
      float a = rl(v, k);
      a0 = fmaf(a, wo0[k], a0);
      a1 = fmaf(a, wo1[k], a1);
    }
    out[(size_t)n * H_DIM + lane] = x[(size_t)n * H_DIM + lane] + a0;
    out[(size_t)n * H_DIM + 64 + lane] = x[(size_t)n * H_DIM + 64 + lane] + a1;
  }
}

extern "C" void kernel_launch(void* const* d_in, const int* in_sizes, int n_in,
                              void* d_out, int out_size, void* d_ws, size_t ws_size,
                              hipStream_t stream) {
  const float* x         = (const float*)d_in[0];
  const float* cji       = (const float*)d_in[1];
  const float* cutoff_w  = (const float*)d_in[2];
  const float* rb        = (const float*)d_in[3];
  const float* shb       = (const float*)d_in[4];
  const int*   idx_i     = (const int*)d_in[5];
  const int*   idx_j     = (const int*)d_in[6];
  const int*   tri_idx_k = (const int*)d_in[7];
  const int*   e_kj      = (const int*)d_in[8];
  const int*   e_ji      = (const int*)d_in[9];
  const float* w_node    = (const float*)d_in[10];
  const float* b_node    = (const float*)d_in[11];
  const float* w_c1      = (const float*)d_in[12];
  const float* w_c2      = (const float*)d_in[13];
  const float* w_t1      = (const float*)d_in[14];
  const float* b_t1      = (const float*)d_in[15];
  const float* w_t2      = (const float*)d_in[16];
  const float* b_t2      = (const float*)d_in[17];
  const float* w_basis   = (const float*)d_in[18];
  const float* w_n1      = (const float*)d_in[19];
  const float* b_n1      = (const float*)d_in[20];
  const float* w_n2      = (const float*)d_in[21];
  const float* b_n2      = (const float*)d_in[22];
  const float* w_out     = (const float*)d_in[23];
  float* out = (float*)d_out;

  char* ws = (char*)d_ws;
  ushort* x1b     = (ushort*)(ws + 0);            //   1,280,000 B
  ushort* sigxkb  = (ushort*)(ws + 1280000);      //   1,280,000 B
  ushort* cji2    = (ushort*)(ws + 2560000);      // 115,200,000 B
  ushort* aggb    = (ushort*)(ws + 117760000);    //  12,800,000 B (bf16 agg)
  ushort* lcaob   = (ushort*)(ws + 143360000);    //  12,800,000 B (bf16)
  ushort* nodeaggb= (ushort*)(ws + 168960000);    //   1,280,000 B (bf16)

  (void)hipMemsetAsync(aggb, 0, (size_t)6400000 * sizeof(ushort), stream);
  (void)hipMemsetAsync(nodeaggb, 0, (size_t)640000 * sizeof(ushort), stream);

  k_node_mlp<<<N_NODES, 128, 0, stream>>>(x, w_node, b_node, x1b, sigxkb);
  k_cji_mlp_mfma<<<2048, 256, 0, stream>>>(cji, w_c1, w_c2, cji2);
  k_triplet_pk<<<2048, 256, 0, stream>>>(cji2, rb, cutoff_w, shb, tri_idx_k,
                                         e_kj, e_ji, sigxkb, aggb);
  k_tbw_lcao<<<1024, 256, 0, stream>>>(aggb, w_t1, b_t1, w_t2, b_t2, cji2,
                                       rb, cutoff_w, w_basis, lcaob);
  k_msg_mfma<<<1024, 256, 0, stream>>>(x1b, idx_i, idx_j, w_n1, b_n1, w_n2,
                                       b_n2, lcaob, nodeaggb);
  k_out<<<256, 256, 0, stream>>>(x, nodeaggb, w_out, out);
}